// Round 2
// baseline (496.354 us; speedup 1.0000x reference)
//
#include <hip/hip_runtime.h>
#include <math.h>

#define HH 1024
#define NN 128
#define MM 512

// ---- output layout (floats) ----
#define OFF_RW 1024
#define OFF_WW 1152
#define OFF_H  1280
#define OFF_C  2304
#define OFF_NM 3328

// ---- workspace layout (floats) ----
#define WS_GATES   0      // 4096
#define WS_CO      4096   // 1024
#define WS_MNORM   5120   // 128
#define WS_A       5248   // 512
#define WS_KR      5760   // 512
#define WS_KW      6272   // 512
#define WS_RSLOG   6784   // 128
#define WS_WSLOG   6912   // 128
#define WS_FCPART  7040   // 1024
#define WS_SCAL    8064   // 6
#define WS_WWV     8072   // 128
#define WS_ERASE   8200   // 512
#define WS_READ    8712   // 512

__device__ __forceinline__ float sigmoidf_(float z) { return 1.f / (1.f + expf(-z)); }
__device__ __forceinline__ float softplusf_(float z) {
    return fmaxf(z, 0.f) + log1pf(expf(-fabsf(z)));
}
__device__ __forceinline__ float wave_reduce(float v) {
    #pragma unroll
    for (int off = 32; off > 0; off >>= 1) v += __shfl_down(v, off, 64);
    return v;
}

// K1: LSTM gates GEMV (4096 rows x 1024, two weight mats) + memory row norms
__global__ __launch_bounds__(256) void k1_gates_norms(
    const float* __restrict__ x, const float* __restrict__ h0,
    const float* __restrict__ W_ih, const float* __restrict__ W_hh,
    const float* __restrict__ b_ih, const float* __restrict__ b_hh,
    const float* __restrict__ memory, float* __restrict__ gates,
    float* __restrict__ mem_norm)
{
    int t = threadIdx.x, lane = t & 63, wv = t >> 6;
    if (blockIdx.x < 1024) {
        int r = blockIdx.x * 4 + wv;  // 0..4095
        const float4* wi = (const float4*)(W_ih + (long long)r * HH);
        const float4* wh = (const float4*)(W_hh + (long long)r * HH);
        const float4* x4 = (const float4*)x;
        const float4* h4 = (const float4*)h0;
        float acc = 0.f;
        #pragma unroll
        for (int q = 0; q < 4; ++q) {
            float4 aa = wi[q * 64 + lane], bb = x4[q * 64 + lane];
            acc += aa.x * bb.x + aa.y * bb.y + aa.z * bb.z + aa.w * bb.w;
        }
        #pragma unroll
        for (int q = 0; q < 4; ++q) {
            float4 aa = wh[q * 64 + lane], bb = h4[q * 64 + lane];
            acc += aa.x * bb.x + aa.y * bb.y + aa.z * bb.z + aa.w * bb.w;
        }
        acc = wave_reduce(acc);
        if (lane == 0) gates[r] = acc + b_ih[r] + b_hh[r];
    } else {
        int n = (blockIdx.x - 1024) * 4 + wv;  // 0..127
        const float4* r4 = (const float4*)(memory + n * MM);
        float acc = 0.f;
        #pragma unroll
        for (int q = 0; q < 2; ++q) {
            float4 aa = r4[q * 64 + lane];
            acc += aa.x * aa.x + aa.y * aa.y + aa.z * aa.z + aa.w * aa.w;
        }
        acc = wave_reduce(acc);
        if (lane == 0) mem_norm[n] = sqrtf(acc);
    }
}

// K2: LSTM nonlinearity -> h, c (to out) and co (to ws); zero erase accumulator
__global__ __launch_bounds__(256) void k2_lstm(
    const float* __restrict__ gates, const float* __restrict__ c0,
    float* __restrict__ out, float* __restrict__ co, float* __restrict__ erase)
{
    int j = blockIdx.x * 256 + threadIdx.x;  // 0..1023
    float gi = gates[j], gf = gates[j + 1024], gg = gates[j + 2048], go = gates[j + 3072];
    float cn = sigmoidf_(gf) * c0[j] + sigmoidf_(gi) * tanhf(gg);
    float hn = sigmoidf_(go) * tanhf(cn);
    out[OFF_H + j] = hn;
    out[OFF_C + j] = cn;
    co[j] = hn;
    if (j < 512) erase[j] = 0.f;
}

// K3s: small co-dependent GEMVs. Virtual rows:
// [0,512) a  [512,1024) kr  [1024,1536) kw  [1536,1664) rs_logit
// [1664,1792) ws_logit  [1792,2816) fc_part  [2816,2822) scalars
#define K3S_ROWS 2822
__global__ __launch_bounds__(256) void k3_small(
    const float* __restrict__ co,
    const float* __restrict__ wa_w, const float* __restrict__ wa_b,
    const float* __restrict__ rk_w, const float* __restrict__ rk_b,
    const float* __restrict__ wk_w, const float* __restrict__ wk_b,
    const float* __restrict__ rs_w, const float* __restrict__ rs_b,
    const float* __restrict__ sw_w, const float* __restrict__ sw_b,
    const float* __restrict__ fc_w, const float* __restrict__ fc_b,
    const float* __restrict__ rbeta_w, const float* __restrict__ rbeta_b,
    const float* __restrict__ rg_w, const float* __restrict__ rg_b,
    const float* __restrict__ rgamma_w, const float* __restrict__ rgamma_b,
    const float* __restrict__ wbeta_w, const float* __restrict__ wbeta_b,
    const float* __restrict__ wg_w, const float* __restrict__ wg_b,
    const float* __restrict__ wgamma_w, const float* __restrict__ wgamma_b,
    float* __restrict__ a, float* __restrict__ kr, float* __restrict__ kw,
    float* __restrict__ rs_logit, float* __restrict__ ws_logit,
    float* __restrict__ fc_part, float* __restrict__ scal)
{
    int t = threadIdx.x, lane = t & 63, wv = t >> 6;
    int r = blockIdx.x * 4 + wv;
    if (r >= K3S_ROWS) return;
    const float* row;
    float bias = 0.f;
    float* dst;
    if (r < 512) {
        row = wa_w + (long long)r * HH; if (lane == 0) bias = wa_b[r]; dst = a + r;
    } else if (r < 1024) {
        int i = r - 512; row = rk_w + (long long)i * HH; if (lane == 0) bias = rk_b[i]; dst = kr + i;
    } else if (r < 1536) {
        int i = r - 1024; row = wk_w + (long long)i * HH; if (lane == 0) bias = wk_b[i]; dst = kw + i;
    } else if (r < 1664) {
        int i = r - 1536; row = rs_w + (long long)i * HH; if (lane == 0) bias = rs_b[i]; dst = rs_logit + i;
    } else if (r < 1792) {
        int i = r - 1664; row = sw_w + (long long)i * HH; if (lane == 0) bias = sw_b[i]; dst = ws_logit + i;
    } else if (r < 2816) {
        int i = r - 1792; row = fc_w + (long long)i * 1536; if (lane == 0) bias = fc_b[i]; dst = fc_part + i;
    } else {
        int i = r - 2816;
        const float* wsrc; const float* bsrc;
        switch (i) {
            case 0: wsrc = rbeta_w;  bsrc = rbeta_b;  break;
            case 1: wsrc = rg_w;     bsrc = rg_b;     break;
            case 2: wsrc = rgamma_w; bsrc = rgamma_b; break;
            case 3: wsrc = wbeta_w;  bsrc = wbeta_b;  break;
            case 4: wsrc = wg_w;     bsrc = wg_b;     break;
            default: wsrc = wgamma_w; bsrc = wgamma_b; break;
        }
        row = wsrc; if (lane == 0) bias = bsrc[0]; dst = scal + i;
    }
    const float4* r4 = (const float4*)row;
    const float4* c4 = (const float4*)co;
    float acc = 0.f;
    #pragma unroll
    for (int q = 0; q < 4; ++q) {
        float4 aa = r4[q * 64 + lane], bb = c4[q * 64 + lane];
        acc += aa.x * bb.x + aa.y * bb.y + aa.z * bb.z + aa.w * bb.w;
    }
    acc = wave_reduce(acc);
    if (lane == 0) *dst = acc + bias;
}

// K4: addressing (block 0 = read head + readv, block 1 = write head)
__global__ __launch_bounds__(256) void k4_address(
    const float* __restrict__ kr, const float* __restrict__ kw,
    const float* __restrict__ scal,
    const float* __restrict__ rs_logit, const float* __restrict__ ws_logit,
    const float* __restrict__ prev_w, const float* __restrict__ mem_norm,
    const float* __restrict__ memory,
    float* __restrict__ out, float* __restrict__ wwv, float* __restrict__ readv)
{
    int head = blockIdx.x;
    int t = threadIdx.x, lane = t & 63, wv = t >> 6;
    const float* k = head ? kw : kr;
    const float* slog = head ? ws_logit : rs_logit;
    float beta  = softplusf_(scal[head ? 3 : 0]);
    float gg    = sigmoidf_(scal[head ? 4 : 1]);
    float gamma = 1.f + softplusf_(scal[head ? 5 : 2]);

    __shared__ float tmp[256];
    __shared__ float s_cos[128];
    __shared__ float s_s[128];
    __shared__ float s_wg[128];
    __shared__ float s_w[128];

    float a0 = k[t], a1 = k[t + 256];
    tmp[t] = a0 * a0 + a1 * a1;
    __syncthreads();
    for (int off = 128; off > 0; off >>= 1) { if (t < off) tmp[t] += tmp[t + off]; __syncthreads(); }
    float k_norm = sqrtf(tmp[0]);
    __syncthreads();

    for (int i = 0; i < 32; ++i) {
        int n = wv * 32 + i;
        const float4* r4 = (const float4*)(memory + n * MM);
        const float4* k4 = (const float4*)k;
        float acc = 0.f;
        #pragma unroll
        for (int q = 0; q < 2; ++q) {
            float4 aa = r4[q * 64 + lane], bb = k4[q * 64 + lane];
            acc += aa.x * bb.x + aa.y * bb.y + aa.z * bb.z + aa.w * bb.w;
        }
        acc = wave_reduce(acc);
        if (lane == 0)
            s_cos[n] = acc / (fmaxf(mem_norm[n], 1e-8f) * fmaxf(k_norm, 1e-8f));
    }
    __syncthreads();

    float z = (t < 128) ? beta * s_cos[t] : -1e30f;
    tmp[t] = z; __syncthreads();
    for (int off = 128; off > 0; off >>= 1) { if (t < off) tmp[t] = fmaxf(tmp[t], tmp[t + off]); __syncthreads(); }
    float zmax = tmp[0]; __syncthreads();
    float ez = (t < 128) ? expf(z - zmax) : 0.f;
    tmp[t] = ez; __syncthreads();
    for (int off = 128; off > 0; off >>= 1) { if (t < off) tmp[t] += tmp[t + off]; __syncthreads(); }
    float zsum = tmp[0]; __syncthreads();
    if (t < 128) s_wg[t] = gg * (ez / zsum) + (1.f - gg) * prev_w[t];

    float sl = (t < 128) ? slog[t] : -1e30f;
    tmp[t] = sl; __syncthreads();
    for (int off = 128; off > 0; off >>= 1) { if (t < off) tmp[t] = fmaxf(tmp[t], tmp[t + off]); __syncthreads(); }
    float smax = tmp[0]; __syncthreads();
    float es = (t < 128) ? expf(sl - smax) : 0.f;
    tmp[t] = es; __syncthreads();
    for (int off = 128; off > 0; off >>= 1) { if (t < off) tmp[t] += tmp[t + off]; __syncthreads(); }
    float ssum = tmp[0]; __syncthreads();
    if (t < 128) s_s[t] = es / ssum;
    __syncthreads();

    float wt = 0.f;
    if (t < 128) {
        #pragma unroll 8
        for (int j = 0; j < 128; ++j) wt += s_wg[j] * s_s[(t - j) & 127];
        wt = powf(wt, gamma);
    }
    tmp[t] = (t < 128) ? wt : 0.f;
    __syncthreads();
    for (int off = 128; off > 0; off >>= 1) { if (t < off) tmp[t] += tmp[t + off]; __syncthreads(); }
    float wsum = tmp[0]; __syncthreads();
    if (t < 128) {
        float wf = wt / (wsum + 1e-16f);
        out[(head ? OFF_WW : OFF_RW) + t] = wf;
        s_w[t] = wf;
        if (head) wwv[t] = wf;
    }
    __syncthreads();

    // read vector: readv[m] = sum_n rw[n] * memory[n, m]  (block 0 only)
    if (head == 0) {
        for (int m = t; m < MM; m += 256) {
            float acc = 0.f;
            #pragma unroll 4
            for (int n = 0; n < NN; ++n) acc += s_w[n] * memory[n * MM + m];
            readv[m] = acc;
        }
    }
}

// K5: big erase GEMV, fused: erase[m] += ww[n] * sigmoid(we_w[row] . co + we_b)
// 65536 rows; 2 rows per wave for MLP; atomics into erase[512].
__global__ __launch_bounds__(256) void k5_bige(
    const float* __restrict__ co,
    const float* __restrict__ we_w, const float* __restrict__ we_b,
    const float* __restrict__ wwv, float* __restrict__ erase)
{
    int t = threadIdx.x, lane = t & 63, wv = t >> 6;
    int wid = blockIdx.x * 4 + wv;         // 0..32767
    long long r0 = (long long)wid * 2;     // rows r0, r0+1
    const float4* w0 = (const float4*)(we_w + r0 * HH);
    const float4* w1 = (const float4*)(we_w + (r0 + 1) * HH);
    const float4* c4 = (const float4*)co;
    float acc0 = 0.f, acc1 = 0.f;
    #pragma unroll
    for (int q = 0; q < 4; ++q) {
        float4 bb = c4[q * 64 + lane];
        float4 a0 = w0[q * 64 + lane];
        float4 a1 = w1[q * 64 + lane];
        acc0 += a0.x * bb.x + a0.y * bb.y + a0.z * bb.z + a0.w * bb.w;
        acc1 += a1.x * bb.x + a1.y * bb.y + a1.z * bb.z + a1.w * bb.w;
    }
    acc0 = wave_reduce(acc0);
    acc1 = wave_reduce(acc1);
    if (lane == 0) {
        int n0 = (int)(r0 >> 9), m0 = (int)(r0 & 511);
        float e0 = sigmoidf_(acc0 + we_b[r0]);
        float e1 = sigmoidf_(acc1 + we_b[r0 + 1]);
        atomicAdd(&erase[m0], wwv[n0] * e0);
        // r0 even: r0+1 has same n unless m0==511
        int n1 = (int)((r0 + 1) >> 9), m1 = (int)((r0 + 1) & 511);
        atomicAdd(&erase[m1], wwv[n1] * e1);
    }
}

// K6: new_mem + fc epilogue
__global__ __launch_bounds__(256) void k6_final(
    const float* __restrict__ memory, const float* __restrict__ erase,
    const float* __restrict__ wwv, const float* __restrict__ a,
    const float* __restrict__ fc_w, const float* __restrict__ fc_part,
    const float* __restrict__ readv, float* __restrict__ out)
{
    int b = blockIdx.x, t = threadIdx.x;
    if (b < 256) {
        int idx = b * 256 + t;
        int n = idx >> 9, m = idx & 511;
        out[OFF_NM + idx] = memory[idx] * (1.f - erase[m]) + wwv[n] * a[m];
    } else {
        int w = (b - 256) * 4 + (t >> 6);  // fc row 0..1023
        int lane = t & 63;
        const float4* r4 = (const float4*)(fc_w + (long long)w * 1536 + 1024);
        const float4* v4 = (const float4*)readv;
        float acc = 0.f;
        #pragma unroll
        for (int q = 0; q < 2; ++q) {
            float4 aa = r4[q * 64 + lane], bb = v4[q * 64 + lane];
            acc += aa.x * bb.x + aa.y * bb.y + aa.z * bb.z + aa.w * bb.w;
        }
        acc = wave_reduce(acc);
        if (lane == 0) out[w] = fc_part[w] + acc;
    }
}

extern "C" void kernel_launch(void* const* d_in, const int* in_sizes, int n_in,
                              void* d_out, int out_size, void* d_ws, size_t ws_size,
                              hipStream_t stream)
{
    const float* x           = (const float*)d_in[0];
    const float* prev_read_w = (const float*)d_in[1];
    // d_in[2] (prev_write_w) unused: reference passes prev_read_w to both heads
    const float* h0      = (const float*)d_in[3];
    const float* c0      = (const float*)d_in[4];
    const float* memory  = (const float*)d_in[5];
    const float* W_ih    = (const float*)d_in[6];
    const float* W_hh    = (const float*)d_in[7];
    const float* b_ih    = (const float*)d_in[8];
    const float* b_hh    = (const float*)d_in[9];
    const float* rk_w    = (const float*)d_in[10];
    const float* rk_b    = (const float*)d_in[11];
    const float* rbeta_w = (const float*)d_in[12];
    const float* rbeta_b = (const float*)d_in[13];
    const float* rg_w    = (const float*)d_in[14];
    const float* rg_b    = (const float*)d_in[15];
    const float* rs_w    = (const float*)d_in[16];
    const float* rs_b    = (const float*)d_in[17];
    const float* rgamma_w = (const float*)d_in[18];
    const float* rgamma_b = (const float*)d_in[19];
    const float* wk_w    = (const float*)d_in[20];
    const float* wk_b    = (const float*)d_in[21];
    const float* wbeta_w = (const float*)d_in[22];
    const float* wbeta_b = (const float*)d_in[23];
    const float* wg_w    = (const float*)d_in[24];
    const float* wg_b    = (const float*)d_in[25];
    const float* sw_w    = (const float*)d_in[26];
    const float* sw_b    = (const float*)d_in[27];
    const float* wgamma_w = (const float*)d_in[28];
    const float* wgamma_b = (const float*)d_in[29];
    const float* we_w    = (const float*)d_in[30];
    const float* we_b    = (const float*)d_in[31];
    const float* wa_w    = (const float*)d_in[32];
    const float* wa_b    = (const float*)d_in[33];
    const float* fc_w    = (const float*)d_in[34];
    const float* fc_b    = (const float*)d_in[35];

    float* ws  = (float*)d_ws;
    float* out = (float*)d_out;

    float* gates    = ws + WS_GATES;
    float* co       = ws + WS_CO;
    float* mem_norm = ws + WS_MNORM;
    float* a        = ws + WS_A;
    float* kr       = ws + WS_KR;
    float* kw       = ws + WS_KW;
    float* rs_logit = ws + WS_RSLOG;
    float* ws_logit = ws + WS_WSLOG;
    float* fc_part  = ws + WS_FCPART;
    float* scal     = ws + WS_SCAL;
    float* wwv      = ws + WS_WWV;
    float* erase    = ws + WS_ERASE;
    float* readv    = ws + WS_READ;

    k1_gates_norms<<<1056, 256, 0, stream>>>(x, h0, W_ih, W_hh, b_ih, b_hh,
                                             memory, gates, mem_norm);
    k2_lstm<<<4, 256, 0, stream>>>(gates, c0, out, co, erase);
    k3_small<<<(K3S_ROWS + 3) / 4, 256, 0, stream>>>(
        co, wa_w, wa_b, rk_w, rk_b, wk_w, wk_b, rs_w, rs_b, sw_w, sw_b,
        fc_w, fc_b,
        rbeta_w, rbeta_b, rg_w, rg_b, rgamma_w, rgamma_b,
        wbeta_w, wbeta_b, wg_w, wg_b, wgamma_w, wgamma_b,
        a, kr, kw, rs_logit, ws_logit, fc_part, scal);
    k4_address<<<2, 256, 0, stream>>>(kr, kw, scal, rs_logit, ws_logit,
                                      prev_read_w, mem_norm, memory,
                                      out, wwv, readv);
    k5_bige<<<8192, 256, 0, stream>>>(co, we_w, we_b, wwv, erase);
    k6_final<<<512, 256, 0, stream>>>(memory, erase, wwv, a, fc_w, fc_part,
                                      readv, out);
}

// Round 3
// 469.324 us; speedup vs baseline: 1.0576x; 1.0576x over previous
//
#include <hip/hip_runtime.h>
#include <math.h>

#define HH 1024
#define NN 128
#define MM 512

typedef float vf4 __attribute__((ext_vector_type(4)));

// ---- output layout (floats) ----
#define OFF_RW 1024
#define OFF_WW 1152
#define OFF_H  1280
#define OFF_C  2304
#define OFF_NM 3328

// ---- workspace layout (floats) ----
#define WS_GATES   0      // 4096
#define WS_CO      4096   // 1024
#define WS_MNORM   5120   // 128
#define WS_A       5248   // 512
#define WS_KR      5760   // 512
#define WS_KW      6272   // 512
#define WS_RSLOG   6784   // 128
#define WS_WSLOG   6912   // 128
#define WS_FCPART  7040   // 1024
#define WS_SCAL    8064   // 6
#define WS_WWV     8072   // 128
#define WS_RWV     8200   // 128
#define WS_ERASE   8328   // 512
#define WS_READ    8840   // 512

__device__ __forceinline__ float sigmoidf_(float z) { return 1.f / (1.f + expf(-z)); }
__device__ __forceinline__ float softplusf_(float z) {
    return fmaxf(z, 0.f) + log1pf(expf(-fabsf(z)));
}
__device__ __forceinline__ float wave_reduce(float v) {
    #pragma unroll
    for (int off = 32; off > 0; off >>= 1) v += __shfl_down(v, off, 64);
    return v;
}
__device__ __forceinline__ float wave_reduce_max(float v) {
    #pragma unroll
    for (int off = 32; off > 0; off >>= 1) v = fmaxf(v, __shfl_down(v, off, 64));
    return v;
}
// 1024-thread block reductions (16 waves), wred[16] in LDS
__device__ __forceinline__ float block_sum(float v, float* wred, int t) {
    __syncthreads();
    float r = wave_reduce(v);
    if ((t & 63) == 0) wred[t >> 6] = r;
    __syncthreads();
    float s = 0.f;
    #pragma unroll
    for (int i = 0; i < 16; ++i) s += wred[i];
    return s;
}
__device__ __forceinline__ float block_max(float v, float* wred, int t) {
    __syncthreads();
    float r = wave_reduce_max(v);
    if ((t & 63) == 0) wred[t >> 6] = r;
    __syncthreads();
    float s = -1e30f;
    #pragma unroll
    for (int i = 0; i < 16; ++i) s = fmaxf(s, wred[i]);
    return s;
}

// K1: LSTM gates GEMV (4096 rows x 1024, two weight mats) + memory row norms
__global__ __launch_bounds__(256) void k1_gates_norms(
    const float* __restrict__ x, const float* __restrict__ h0,
    const float* __restrict__ W_ih, const float* __restrict__ W_hh,
    const float* __restrict__ b_ih, const float* __restrict__ b_hh,
    const float* __restrict__ memory, float* __restrict__ gates,
    float* __restrict__ mem_norm)
{
    int t = threadIdx.x, lane = t & 63, wv = t >> 6;
    if (blockIdx.x < 1024) {
        int r = blockIdx.x * 4 + wv;  // 0..4095
        const vf4* wi = (const vf4*)(W_ih + (long long)r * HH);
        const vf4* wh = (const vf4*)(W_hh + (long long)r * HH);
        const vf4* x4 = (const vf4*)x;
        const vf4* h4 = (const vf4*)h0;
        float acc = 0.f;
        #pragma unroll
        for (int q = 0; q < 4; ++q) {
            vf4 aa = __builtin_nontemporal_load(&wi[q * 64 + lane]);
            vf4 bb = x4[q * 64 + lane];
            acc += aa[0] * bb[0] + aa[1] * bb[1] + aa[2] * bb[2] + aa[3] * bb[3];
        }
        #pragma unroll
        for (int q = 0; q < 4; ++q) {
            vf4 aa = __builtin_nontemporal_load(&wh[q * 64 + lane]);
            vf4 bb = h4[q * 64 + lane];
            acc += aa[0] * bb[0] + aa[1] * bb[1] + aa[2] * bb[2] + aa[3] * bb[3];
        }
        acc = wave_reduce(acc);
        if (lane == 0) gates[r] = acc + b_ih[r] + b_hh[r];
    } else {
        int n = (blockIdx.x - 1024) * 4 + wv;  // 0..127
        const vf4* r4 = (const vf4*)(memory + n * MM);
        float acc = 0.f;
        #pragma unroll
        for (int q = 0; q < 2; ++q) {
            vf4 aa = r4[q * 64 + lane];
            acc += aa[0] * aa[0] + aa[1] * aa[1] + aa[2] * aa[2] + aa[3] * aa[3];
        }
        acc = wave_reduce(acc);
        if (lane == 0) mem_norm[n] = sqrtf(acc);
    }
}

// K2: LSTM nonlinearity -> h, c (to out) and co (to ws); zero erase accumulator
__global__ __launch_bounds__(256) void k2_lstm(
    const float* __restrict__ gates, const float* __restrict__ c0,
    float* __restrict__ out, float* __restrict__ co, float* __restrict__ erase)
{
    int j = blockIdx.x * 256 + threadIdx.x;  // 0..1023
    float gi = gates[j], gf = gates[j + 1024], gg = gates[j + 2048], go = gates[j + 3072];
    float cn = sigmoidf_(gf) * c0[j] + sigmoidf_(gi) * tanhf(gg);
    float hn = sigmoidf_(go) * tanhf(cn);
    out[OFF_H + j] = hn;
    out[OFF_C + j] = cn;
    co[j] = hn;
    if (j < 512) erase[j] = 0.f;
}

// K3s: small co-dependent GEMVs. Virtual rows:
// [0,512) a  [512,1024) kr  [1024,1536) kw  [1536,1664) rs_logit
// [1664,1792) ws_logit  [1792,2816) fc_part  [2816,2822) scalars
#define K3S_ROWS 2822
__global__ __launch_bounds__(256) void k3_small(
    const float* __restrict__ co,
    const float* __restrict__ wa_w, const float* __restrict__ wa_b,
    const float* __restrict__ rk_w, const float* __restrict__ rk_b,
    const float* __restrict__ wk_w, const float* __restrict__ wk_b,
    const float* __restrict__ rs_w, const float* __restrict__ rs_b,
    const float* __restrict__ sw_w, const float* __restrict__ sw_b,
    const float* __restrict__ fc_w, const float* __restrict__ fc_b,
    const float* __restrict__ rbeta_w, const float* __restrict__ rbeta_b,
    const float* __restrict__ rg_w, const float* __restrict__ rg_b,
    const float* __restrict__ rgamma_w, const float* __restrict__ rgamma_b,
    const float* __restrict__ wbeta_w, const float* __restrict__ wbeta_b,
    const float* __restrict__ wg_w, const float* __restrict__ wg_b,
    const float* __restrict__ wgamma_w, const float* __restrict__ wgamma_b,
    float* __restrict__ a, float* __restrict__ kr, float* __restrict__ kw,
    float* __restrict__ rs_logit, float* __restrict__ ws_logit,
    float* __restrict__ fc_part, float* __restrict__ scal)
{
    int t = threadIdx.x, lane = t & 63, wv = t >> 6;
    int r = blockIdx.x * 4 + wv;
    if (r >= K3S_ROWS) return;
    const float* row;
    float bias = 0.f;
    float* dst;
    if (r < 512) {
        row = wa_w + (long long)r * HH; if (lane == 0) bias = wa_b[r]; dst = a + r;
    } else if (r < 1024) {
        int i = r - 512; row = rk_w + (long long)i * HH; if (lane == 0) bias = rk_b[i]; dst = kr + i;
    } else if (r < 1536) {
        int i = r - 1024; row = wk_w + (long long)i * HH; if (lane == 0) bias = wk_b[i]; dst = kw + i;
    } else if (r < 1664) {
        int i = r - 1536; row = rs_w + (long long)i * HH; if (lane == 0) bias = rs_b[i]; dst = rs_logit + i;
    } else if (r < 1792) {
        int i = r - 1664; row = sw_w + (long long)i * HH; if (lane == 0) bias = sw_b[i]; dst = ws_logit + i;
    } else if (r < 2816) {
        int i = r - 1792; row = fc_w + (long long)i * 1536; if (lane == 0) bias = fc_b[i]; dst = fc_part + i;
    } else {
        int i = r - 2816;
        const float* wsrc; const float* bsrc;
        switch (i) {
            case 0: wsrc = rbeta_w;  bsrc = rbeta_b;  break;
            case 1: wsrc = rg_w;     bsrc = rg_b;     break;
            case 2: wsrc = rgamma_w; bsrc = rgamma_b; break;
            case 3: wsrc = wbeta_w;  bsrc = wbeta_b;  break;
            case 4: wsrc = wg_w;     bsrc = wg_b;     break;
            default: wsrc = wgamma_w; bsrc = wgamma_b; break;
        }
        row = wsrc; if (lane == 0) bias = bsrc[0]; dst = scal + i;
    }
    const vf4* r4 = (const vf4*)row;
    const vf4* c4 = (const vf4*)co;
    float acc = 0.f;
    #pragma unroll
    for (int q = 0; q < 4; ++q) {
        vf4 aa = r4[q * 64 + lane], bb = c4[q * 64 + lane];
        acc += aa[0] * bb[0] + aa[1] * bb[1] + aa[2] * bb[2] + aa[3] * bb[3];
    }
    acc = wave_reduce(acc);
    if (lane == 0) *dst = acc + bias;
}

// K4: addressing, 1024 threads/block; block 0 = read head, block 1 = write head
__global__ __launch_bounds__(1024) void k4_address(
    const float* __restrict__ kr, const float* __restrict__ kw,
    const float* __restrict__ scal,
    const float* __restrict__ rs_logit, const float* __restrict__ ws_logit,
    const float* __restrict__ prev_w, const float* __restrict__ mem_norm,
    const float* __restrict__ memory,
    float* __restrict__ out, float* __restrict__ rwv, float* __restrict__ wwv)
{
    int head = blockIdx.x;
    int t = threadIdx.x, lane = t & 63, wv = t >> 6;  // 16 waves
    const float* k = head ? kw : kr;
    const float* slog = head ? ws_logit : rs_logit;
    float beta  = softplusf_(scal[head ? 3 : 0]);
    float gg    = sigmoidf_(scal[head ? 4 : 1]);
    float gamma = 1.f + softplusf_(scal[head ? 5 : 2]);

    __shared__ float wred[16];
    __shared__ float s_cos[128];
    __shared__ float s_s[128];
    __shared__ float s_wg[128];

    // ||k||
    float kv = (t < 512) ? k[t] : 0.f;
    float k_norm = sqrtf(block_sum(kv * kv, wred, t));

    // cos rows: 16 waves x 8 rows
    const vf4* k4p = (const vf4*)k;
    vf4 bb0 = k4p[lane], bb1 = k4p[64 + lane];
    #pragma unroll
    for (int i = 0; i < 8; ++i) {
        int n = wv * 8 + i;
        const vf4* r4 = (const vf4*)(memory + n * MM);
        vf4 a0 = r4[lane], a1 = r4[64 + lane];
        float acc = a0[0] * bb0[0] + a0[1] * bb0[1] + a0[2] * bb0[2] + a0[3] * bb0[3]
                  + a1[0] * bb1[0] + a1[1] * bb1[1] + a1[2] * bb1[2] + a1[3] * bb1[3];
        acc = wave_reduce(acc);
        if (lane == 0)
            s_cos[n] = acc / (fmaxf(mem_norm[n], 1e-8f) * fmaxf(k_norm, 1e-8f));
    }
    __syncthreads();

    // w_c = softmax(beta*cos); w_g = g*w_c + (1-g)*prev_read_w
    float z = (t < 128) ? beta * s_cos[t] : -1e30f;
    float zmax = block_max(z, wred, t);
    float ez = (t < 128) ? expf(z - zmax) : 0.f;
    float zsum = block_sum(ez, wred, t);
    if (t < 128) s_wg[t] = gg * (ez / zsum) + (1.f - gg) * prev_w[t];

    // s = softmax(s_logit)
    float sl = (t < 128) ? slog[t] : -1e30f;
    float smax = block_max(sl, wred, t);
    float es = (t < 128) ? expf(sl - smax) : 0.f;
    float ssum = block_sum(es, wred, t);
    if (t < 128) s_s[t] = es / ssum;
    __syncthreads();

    // circular conv + sharpen
    float wt = 0.f;
    if (t < 128) {
        #pragma unroll 8
        for (int j = 0; j < 128; ++j) wt += s_wg[j] * s_s[(t - j) & 127];
        wt = powf(wt, gamma);
    }
    float wsum = block_sum((t < 128) ? wt : 0.f, wred, t);
    if (t < 128) {
        float wf = wt / (wsum + 1e-16f);
        out[(head ? OFF_WW : OFF_RW) + t] = wf;
        (head ? wwv : rwv)[t] = wf;
    }
}

// K5: big erase GEMV fused with sigmoid + ww-contraction (blocks 0..4095),
// plus readv contraction (blocks 4096..4097).
__global__ __launch_bounds__(256) void k5_bige(
    const float* __restrict__ co,
    const float* __restrict__ we_w, const float* __restrict__ we_b,
    const float* __restrict__ wwv, float* __restrict__ erase,
    const float* __restrict__ rwv, const float* __restrict__ memory,
    float* __restrict__ readv)
{
    int t = threadIdx.x, lane = t & 63, wv = t >> 6;
    int b = blockIdx.x;
    if (b < 4096) {
        int wid = b * 4 + wv;              // 0..16383
        long long r0 = (long long)wid * 4; // rows r0..r0+3 (same n)
        const vf4* c4 = (const vf4*)co;
        const float* base = we_w + r0 * HH;
        float acc0 = 0.f, acc1 = 0.f, acc2 = 0.f, acc3 = 0.f;
        #pragma unroll
        for (int q = 0; q < 4; ++q) {
            vf4 bb = c4[q * 64 + lane];
            vf4 a0 = __builtin_nontemporal_load((const vf4*)(base) + q * 64 + lane);
            vf4 a1 = __builtin_nontemporal_load((const vf4*)(base + HH) + q * 64 + lane);
            vf4 a2 = __builtin_nontemporal_load((const vf4*)(base + 2 * HH) + q * 64 + lane);
            vf4 a3 = __builtin_nontemporal_load((const vf4*)(base + 3 * HH) + q * 64 + lane);
            acc0 += a0[0] * bb[0] + a0[1] * bb[1] + a0[2] * bb[2] + a0[3] * bb[3];
            acc1 += a1[0] * bb[0] + a1[1] * bb[1] + a1[2] * bb[2] + a1[3] * bb[3];
            acc2 += a2[0] * bb[0] + a2[1] * bb[1] + a2[2] * bb[2] + a2[3] * bb[3];
            acc3 += a3[0] * bb[0] + a3[1] * bb[1] + a3[2] * bb[2] + a3[3] * bb[3];
        }
        acc0 = wave_reduce(acc0);
        acc1 = wave_reduce(acc1);
        acc2 = wave_reduce(acc2);
        acc3 = wave_reduce(acc3);
        if (lane == 0) {
            int n = (int)(r0 >> 9), m0 = (int)(r0 & 511);
            float wn = wwv[n];
            float e0 = sigmoidf_(acc0 + we_b[r0]);
            float e1 = sigmoidf_(acc1 + we_b[r0 + 1]);
            float e2 = sigmoidf_(acc2 + we_b[r0 + 2]);
            float e3 = sigmoidf_(acc3 + we_b[r0 + 3]);
            atomicAdd(&erase[m0],     wn * e0);
            atomicAdd(&erase[m0 + 1], wn * e1);
            atomicAdd(&erase[m0 + 2], wn * e2);
            atomicAdd(&erase[m0 + 3], wn * e3);
        }
    } else {
        __shared__ float s_rw[128];
        if (t < 128) s_rw[t] = rwv[t];
        __syncthreads();
        int m = (b - 4096) * 256 + t;
        float acc = 0.f;
        #pragma unroll 4
        for (int n = 0; n < NN; ++n) acc += s_rw[n] * memory[n * MM + m];
        readv[m] = acc;
    }
}

// K6: new_mem + fc epilogue
__global__ __launch_bounds__(256) void k6_final(
    const float* __restrict__ memory, const float* __restrict__ erase,
    const float* __restrict__ wwv, const float* __restrict__ a,
    const float* __restrict__ fc_w, const float* __restrict__ fc_part,
    const float* __restrict__ readv, float* __restrict__ out)
{
    int b = blockIdx.x, t = threadIdx.x;
    if (b < 256) {
        int idx = b * 256 + t;
        int n = idx >> 9, m = idx & 511;
        out[OFF_NM + idx] = memory[idx] * (1.f - erase[m]) + wwv[n] * a[m];
    } else {
        int w = (b - 256) * 4 + (t >> 6);  // fc row 0..1023
        int lane = t & 63;
        const vf4* r4 = (const vf4*)(fc_w + (long long)w * 1536 + 1024);
        const vf4* v4 = (const vf4*)readv;
        float acc = 0.f;
        #pragma unroll
        for (int q = 0; q < 2; ++q) {
            vf4 aa = r4[q * 64 + lane], bb = v4[q * 64 + lane];
            acc += aa[0] * bb[0] + aa[1] * bb[1] + aa[2] * bb[2] + aa[3] * bb[3];
        }
        acc = wave_reduce(acc);
        if (lane == 0) out[w] = fc_part[w] + acc;
    }
}

extern "C" void kernel_launch(void* const* d_in, const int* in_sizes, int n_in,
                              void* d_out, int out_size, void* d_ws, size_t ws_size,
                              hipStream_t stream)
{
    const float* x           = (const float*)d_in[0];
    const float* prev_read_w = (const float*)d_in[1];
    // d_in[2] (prev_write_w) unused: reference passes prev_read_w to both heads
    const float* h0      = (const float*)d_in[3];
    const float* c0      = (const float*)d_in[4];
    const float* memory  = (const float*)d_in[5];
    const float* W_ih    = (const float*)d_in[6];
    const float* W_hh    = (const float*)d_in[7];
    const float* b_ih    = (const float*)d_in[8];
    const float* b_hh    = (const float*)d_in[9];
    const float* rk_w    = (const float*)d_in[10];
    const float* rk_b    = (const float*)d_in[11];
    const float* rbeta_w = (const float*)d_in[12];
    const float* rbeta_b = (const float*)d_in[13];
    const float* rg_w    = (const float*)d_in[14];
    const float* rg_b    = (const float*)d_in[15];
    const float* rs_w    = (const float*)d_in[16];
    const float* rs_b    = (const float*)d_in[17];
    const float* rgamma_w = (const float*)d_in[18];
    const float* rgamma_b = (const float*)d_in[19];
    const float* wk_w    = (const float*)d_in[20];
    const float* wk_b    = (const float*)d_in[21];
    const float* wbeta_w = (const float*)d_in[22];
    const float* wbeta_b = (const float*)d_in[23];
    const float* wg_w    = (const float*)d_in[24];
    const float* wg_b    = (const float*)d_in[25];
    const float* sw_w    = (const float*)d_in[26];
    const float* sw_b    = (const float*)d_in[27];
    const float* wgamma_w = (const float*)d_in[28];
    const float* wgamma_b = (const float*)d_in[29];
    const float* we_w    = (const float*)d_in[30];
    const float* we_b    = (const float*)d_in[31];
    const float* wa_w    = (const float*)d_in[32];
    const float* wa_b    = (const float*)d_in[33];
    const float* fc_w    = (const float*)d_in[34];
    const float* fc_b    = (const float*)d_in[35];

    float* ws  = (float*)d_ws;
    float* out = (float*)d_out;

    float* gates    = ws + WS_GATES;
    float* co       = ws + WS_CO;
    float* mem_norm = ws + WS_MNORM;
    float* a        = ws + WS_A;
    float* kr       = ws + WS_KR;
    float* kw       = ws + WS_KW;
    float* rs_logit = ws + WS_RSLOG;
    float* ws_logit = ws + WS_WSLOG;
    float* fc_part  = ws + WS_FCPART;
    float* scal     = ws + WS_SCAL;
    float* wwv      = ws + WS_WWV;
    float* rwv      = ws + WS_RWV;
    float* erase    = ws + WS_ERASE;
    float* readv    = ws + WS_READ;

    k1_gates_norms<<<1056, 256, 0, stream>>>(x, h0, W_ih, W_hh, b_ih, b_hh,
                                             memory, gates, mem_norm);
    k2_lstm<<<4, 256, 0, stream>>>(gates, c0, out, co, erase);
    k3_small<<<(K3S_ROWS + 3) / 4, 256, 0, stream>>>(
        co, wa_w, wa_b, rk_w, rk_b, wk_w, wk_b, rs_w, rs_b, sw_w, sw_b,
        fc_w, fc_b,
        rbeta_w, rbeta_b, rg_w, rg_b, rgamma_w, rgamma_b,
        wbeta_w, wbeta_b, wg_w, wg_b, wgamma_w, wgamma_b,
        a, kr, kw, rs_logit, ws_logit, fc_part, scal);
    k4_address<<<2, 1024, 0, stream>>>(kr, kw, scal, rs_logit, ws_logit,
                                       prev_read_w, mem_norm, memory,
                                       out, rwv, wwv);
    k5_bige<<<4098, 256, 0, stream>>>(co, we_w, we_b, wwv, erase,
                                      rwv, memory, readv);
    k6_final<<<512, 256, 0, stream>>>(memory, erase, wwv, a, fc_w, fc_part,
                                      readv, out);
}